// Round 17
// baseline (100.930 us; speedup 1.0000x reference)
//
#include <hip/hip_runtime.h>
#include <hip/hip_bf16.h>

#define D_ 128
#define S_ 512
#define B_ 4
#define H_ 8

typedef short bf16x8 __attribute__((ext_vector_type(8)));
typedef unsigned int u32x4 __attribute__((ext_vector_type(4)));
typedef float f32x4 __attribute__((ext_vector_type(4)));
typedef float f32x2 __attribute__((ext_vector_type(2)));

__device__ __forceinline__ short f2bf(float f) {
  __hip_bfloat16 h = __float2bfloat16(f);
  return __builtin_bit_cast(short, h);
}
__device__ __forceinline__ float fsigmoid(float x) {
  return __builtin_amdgcn_rcpf(1.0f + __expf(-x));
}
// HW packed f32->bf16 (RNE) — verified r9/r14.
__device__ __forceinline__ unsigned int cvt_pk_bf16(float lo, float hi) {
  unsigned int r;
  asm("v_cvt_pk_bf16_f32 %0, %1, %2" : "=v"(r) : "v"(lo), "v"(hi));
  return r;
}

// Fused single-launch kernel. Block = (b, jh, ig); group g=(b,jh) = 64
// consecutive blocks. P-phase: block produces the 4 C-rows (jh*256+ig*4..+3,
// bf16 -> ws) its group needs, plus its own 8 A-rows (f32 -> LDS, b1 folded).
// Group sync: per-writer release fence + release-add on flags[g]; relaxed
// spin + s_sleep + one acquire load (device scope, G16-compliant).
// Then: stage group-complete C (ws bf16 -> LDS, XOR-swizzled, pure copy) and
// run the r9-verbatim main loop (verified absmax 3.9e-3).
// Capacity: 74KB LDS, <=128 VGPR -> 2 blocks/CU x 256 CU = 512 = grid, all
// co-resident; waits are group-local over consecutively-dispatched blocks.
__global__ __launch_bounds__(512, 4)
void fused_kernel(const float* __restrict__ x, const float* __restrict__ w1,
                  const float* __restrict__ b1, const float* __restrict__ w2,
                  const float* __restrict__ b2, float* __restrict__ out,
                  short* __restrict__ Cws, int* __restrict__ flags) {
  __shared__ short cbf[256 * D_];   // 64 KB: C half, bf16, swizzled
  __shared__ float xs[12 * D_];     // 6 KB: 4 C-src + 8 A-src x rows
  __shared__ float alds[8 * D_];    // 4 KB: a rows (f32, b1 folded)

  const int t = threadIdx.x;
  const int lane = t & 63;
  const int wid = t >> 6;                // 0..7
  const int b  = blockIdx.x >> 7;
  const int jh = (blockIdx.x >> 6) & 1;
  const int ig = blockIdx.x & 63;
  const int i  = ig * 8 + wid;
  const int g  = b * 2 + jh;

  const int jcol = lane & 15;
  const int lgrp = lane >> 4;
  const int sw = jcol & 7;

  // ---- P0: stage 12 x rows (4 C-src, 8 A-src)
  if (t < 384) {
    int row = t >> 5, f4 = (t & 31) * 4;
    int gr = (row < 4) ? (jh * 256 + ig * 4 + row) : (ig * 8 + (row - 4));
    *(float4*)(xs + row * D_ + f4) =
        *(const float4*)(x + (size_t)(b * S_ + gr) * D_ + f4);
  }
  __syncthreads();

  // ---- P1: produce C rows (t<128) and A rows (128<=t<384)
  if (t < 128) {
    int r = t >> 5, e4 = (t & 31) * 4;
    const float* xr = xs + r * D_;
    f32x4 acc = {0.f, 0.f, 0.f, 0.f};
    #pragma unroll 8
    for (int k = 0; k < D_; ++k) {
      float4 wv = *(const float4*)(w1 + (D_ + k) * D_ + e4);
      float xv = xr[k];
      acc[0] += xv * wv.x; acc[1] += xv * wv.y;
      acc[2] += xv * wv.z; acc[3] += xv * wv.w;
    }
    uint2 u;
    u.x = cvt_pk_bf16(acc[0], acc[1]);
    u.y = cvt_pk_bf16(acc[2], acc[3]);
    *(uint2*)(Cws + ((size_t)(b * S_) + jh * 256 + ig * 4 + r) * D_ + e4) = u;
    __threadfence();                      // release my C stores (device scope)
  } else if (t < 384) {
    int u2 = t - 128;
    int ar = u2 >> 5, e4 = (u2 & 31) * 4;
    const float* xr = xs + (4 + ar) * D_;
    f32x4 acc = {0.f, 0.f, 0.f, 0.f};
    #pragma unroll 8
    for (int k = 0; k < D_; ++k) {
      float4 wv = *(const float4*)(w1 + k * D_ + e4);
      float xv = xr[k];
      acc[0] += xv * wv.x; acc[1] += xv * wv.y;
      acc[2] += xv * wv.z; acc[3] += xv * wv.w;
    }
    float4 bv = *(const float4*)(b1 + e4);
    acc[0] += bv.x; acc[1] += bv.y; acc[2] += bv.z; acc[3] += bv.w;
    *(f32x4*)(alds + ar * D_ + e4) = acc;
  }
  __syncthreads();

  // ---- group sync: signal, then wait for all 64 producers of (b,jh)
  if (t == 0) {
    __hip_atomic_fetch_add(&flags[g], 1, __ATOMIC_RELEASE,
                           __HIP_MEMORY_SCOPE_AGENT);
    while (__hip_atomic_load(&flags[g], __ATOMIC_RELAXED,
                             __HIP_MEMORY_SCOPE_AGENT) < 64)
      __builtin_amdgcn_s_sleep(2);
    (void)__hip_atomic_load(&flags[g], __ATOMIC_ACQUIRE,
                            __HIP_MEMORY_SCOPE_AGENT);   // one inv
  }
  __syncthreads();

  // ---- stage C half (ws bf16, group-complete) -> LDS swizzled (pure copy)
  {
    const short* cb = Cws + (size_t)(b * S_ + jh * 256) * D_;
    #pragma unroll
    for (int it = 0; it < 8; ++it) {
      int p = t + it * 512;
      int row = p >> 4, u = p & 15;
      u32x4 v = *(const u32x4*)(cb + row * D_ + u * 8);
      *(u32x4*)(cbf + row * D_ + (u ^ (row & 7)) * 8) = v;
    }
  }

  // ---- main-loop setup (r9 verbatim; apk from alds)
  f32x2 apk[4][4];
  {
    const float* Ai = alds + wid * D_ + lgrp * 8;
    #pragma unroll
    for (int ch = 0; ch < 4; ++ch) {
      f32x4 v0 = *(const f32x4*)(Ai + ch * 32);
      f32x4 v1 = *(const f32x4*)(Ai + ch * 32 + 4);
      apk[ch][0][0] = v0[0]; apk[ch][0][1] = v0[1];
      apk[ch][1][0] = v0[2]; apk[ch][1][1] = v0[3];
      apk[ch][2][0] = v1[0]; apk[ch][2][1] = v1[1];
      apk[ch][3][0] = v1[2]; apk[ch][3][1] = v1[3];
    }
  }
  bf16x8 w2f[4];
  #pragma unroll
  for (int ch = 0; ch < 4; ++ch) {
    #pragma unroll
    for (int e = 0; e < 8; ++e) {
      float wv = (jcol < H_) ? w2[(ch * 32 + lgrp * 8 + e) * H_ + jcol] : 0.0f;
      w2f[ch][e] = f2bf(wv);
    }
  }
  const float b2v = (jcol < H_) ? b2[jcol] : 0.0f;
  float* outp = out + (((size_t)(b * H_ + (jcol & 7)) * S_ + i) * S_)
                + jh * 256 + lgrp * 4;
  __syncthreads();                       // C staged

  u32x4 cva[4], cvb[4];
  auto LOADT = [&](u32x4 (&dst)[4], int jt) {
    const short* bp = cbf + (jt * 16 + jcol) * D_;
    #pragma unroll
    for (int ch = 0; ch < 4; ++ch)
      dst[ch] = *(const u32x4*)(bp + (((ch * 4 + lgrp) ^ sw) * 8));
  };
  auto COMPUTE = [&](u32x4 (&cv)[4], int jt) {   // r9 verbatim
    f32x4 acc = {0.f, 0.f, 0.f, 0.f};
    #pragma unroll
    for (int ch = 0; ch < 4; ++ch) {
      u32x4 hfd;
      #pragma unroll
      for (int p = 0; p < 4; ++p) {
        unsigned int d = cv[ch][p];
        f32x2 v;
        v[0] = __builtin_bit_cast(float, d << 16);
        v[1] = __builtin_bit_cast(float, d & 0xffff0000u);
        v += apk[ch][p];
        hfd[p] = cvt_pk_bf16(fmaxf(v[0], 0.f), fmaxf(v[1], 0.f));
      }
      bf16x8 hf = __builtin_bit_cast(bf16x8, hfd);
      acc = __builtin_amdgcn_mfma_f32_16x16x32_bf16(hf, w2f[ch], acc, 0, 0, 0);
    }
    if (jcol < H_) {
      float4 o;
      o.x = fsigmoid(acc[0] + b2v);
      o.y = fsigmoid(acc[1] + b2v);
      o.z = fsigmoid(acc[2] + b2v);
      o.w = fsigmoid(acc[3] + b2v);
      *(float4*)(outp + jt * 16) = o;
    }
  };

  LOADT(cva, 0);
  #pragma unroll 1
  for (int jt = 0; jt < 16; jt += 2) {
    LOADT(cvb, jt + 1);
    COMPUTE(cva, jt);
    LOADT(cva, (jt + 2) & 15);           // wrap harmless
    COMPUTE(cvb, jt + 1);
  }
}

extern "C" void kernel_launch(void* const* d_in, const int* in_sizes, int n_in,
                              void* d_out, int out_size, void* d_ws, size_t ws_size,
                              hipStream_t stream) {
  const float* x  = (const float*)d_in[0];
  const float* w1 = (const float*)d_in[1];
  const float* b1 = (const float*)d_in[2];
  const float* w2 = (const float*)d_in[3];
  const float* b2 = (const float*)d_in[4];
  float* out = (float*)d_out;
  short* Cws = (short*)d_ws;                              // 512 KB bf16 C
  int* flags = (int*)((char*)d_ws + (size_t)B_ * S_ * D_ * 2);  // 8 ints
  // Re-zero flags every call/replay (graph-capturable async memset).
  hipMemsetAsync(flags, 0, 8 * sizeof(int), stream);
  fused_kernel<<<B_ * 2 * 64, 512, 0, stream>>>(x, w1, b1, w2, b2, out,
                                                Cws, flags);
}

// Round 18
// 88.610 us; speedup vs baseline: 1.1390x; 1.1390x over previous
//
#include <hip/hip_runtime.h>
#include <hip/hip_bf16.h>

#define D_ 128
#define S_ 512
#define B_ 4
#define H_ 8

typedef short bf16x8 __attribute__((ext_vector_type(8)));
typedef unsigned int u32x4 __attribute__((ext_vector_type(4)));
typedef float f32x4 __attribute__((ext_vector_type(4)));
typedef float f32x2 __attribute__((ext_vector_type(2)));

__device__ __forceinline__ short f2bf(float f) {
  __hip_bfloat16 h = __float2bfloat16(f);
  return __builtin_bit_cast(short, h);
}
__device__ __forceinline__ float fsigmoid(float x) {
  return __builtin_amdgcn_rcpf(1.0f + __expf(-x));
}
// HW packed f32->bf16 (RNE) — verified r9/r14.
__device__ __forceinline__ unsigned int cvt_pk_bf16(float lo, float hi) {
  unsigned int r;
  asm("v_cvt_pk_bf16_f32 %0, %1, %2" : "=v"(r) : "v"(lo), "v"(hi));
  return r;
}

// Proj v4 (r14 verbatim, verified absmax 3.9e-3): A (+b1) -> f32 Aq,
// C -> bf16 Cbf (cvt_pk_bf16). 512 blocks x 256 thr; w1 read once/block.
__global__ __launch_bounds__(256)
void proj_kernel(const float* __restrict__ x, const float* __restrict__ w1,
                 const float* __restrict__ b1, float* __restrict__ Aq,
                 short* __restrict__ Cbf) {
  __shared__ float xs[4 * D_];
  __shared__ f32x4 red[256][5];
  const int t = threadIdx.x;
  const int row0 = blockIdx.x * 4;
  ((float2*)xs)[t] = ((const float2*)(x + row0 * D_))[t];
  __syncthreads();
  const int combo = t & 63;
  const int e4 = (combo & 31) * 4;
  const int half = combo >> 5;
  const int kq = t >> 6;
  const float* w1p = w1 + (half * D_ + kq * 32) * D_ + e4;
  const float* xq = xs + kq * 32;
  f32x4 acc[4] = {};
  #pragma unroll 8
  for (int k = 0; k < 32; ++k) {
    float4 wv = *(const float4*)(w1p + k * D_);
    #pragma unroll
    for (int r = 0; r < 4; ++r) {
      float xv = xq[r * D_ + k];
      acc[r][0] += xv * wv.x; acc[r][1] += xv * wv.y;
      acc[r][2] += xv * wv.z; acc[r][3] += xv * wv.w;
    }
  }
  #pragma unroll
  for (int r = 0; r < 4; ++r) red[t][r] = acc[r];
  __syncthreads();
  const int r = t >> 6;
  const int c2 = t & 63;
  f32x4 s = red[c2][r];
  #pragma unroll
  for (int q = 1; q < 4; ++q) {
    f32x4 v = red[c2 + 64 * q][r];
    s[0] += v[0]; s[1] += v[1]; s[2] += v[2]; s[3] += v[3];
  }
  const int fe4 = (c2 & 31) * 4;
  const int row = row0 + r;
  if ((c2 >> 5) == 0) {
    float4 bv = *(const float4*)(b1 + fe4);
    s[0] += bv.x; s[1] += bv.y; s[2] += bv.z; s[3] += bv.w;
    *(f32x4*)(Aq + row * D_ + fe4) = s;
  } else {
    uint2 u;
    u.x = cvt_pk_bf16(s[0], s[1]);
    u.y = cvt_pk_bf16(s[2], s[3]);
    *(uint2*)(Cbf + row * D_ + fe4) = u;
  }
}

// Edge v8: j-QUARTER split for occupancy. Block = (b, jq, ig); 32 KB LDS
// (128 C-rows, bf16, XOR-swizzled, staged as PURE COPY from Cbf) -> 4
// blocks/CU = 8 waves/SIMD (launch_bounds(512,8); loop codegen is 48-56
// VGPR <= 64 cap, r8/r14-measured). Main loop: 8 j-tiles, dbuf prefetch,
// r9-verbatim COMPUTE (verified absmax 3.9e-3).
// MFMA A: row=lane&15 (=j), k=8*(lane>>4)+e. D: col=lane&15 (=h),
// row=(lane>>4)*4+reg. (verified r2-r14)
__global__ __launch_bounds__(512, 8)
void edge_kernel(const float* __restrict__ Aq, const short* __restrict__ Cbf,
                 const float* __restrict__ w2, const float* __restrict__ b2,
                 float* __restrict__ out) {
  __shared__ short cbf[128 * D_];        // 32 KB
  const int t = threadIdx.x;
  const int lane = t & 63;
  const int wid = t >> 6;                // 0..7
  const int b  = blockIdx.x >> 8;
  const int jq = (blockIdx.x >> 6) & 3;  // j quarter
  const int ig = blockIdx.x & 63;
  const int i  = ig * 8 + wid;

  const int jcol = lane & 15;            // j within tile == output h
  const int lgrp = lane >> 4;            // k-group
  const int sw = jcol & 7;

  // ---- stage C quarter (bf16 -> bf16, pure copy, swizzled): 4 iters
  {
    const short* cb = Cbf + (size_t)(b * S_ + jq * 128) * D_;
    #pragma unroll
    for (int it = 0; it < 4; ++it) {
      int p = t + it * 512;
      int row = p >> 4, u = p & 15;
      u32x4 v = *(const u32x4*)(cb + row * D_ + u * 8);
      *(u32x4*)(cbf + row * D_ + (u ^ (row & 7)) * 8) = v;
    }
  }

  // a registers as packed f32x2 (b1 folded in proj) — r9 verbatim
  f32x2 apk[4][4];
  {
    const float* Ai = Aq + (b * S_ + i) * D_ + lgrp * 8;
    #pragma unroll
    for (int ch = 0; ch < 4; ++ch) {
      float4 v0 = *(const float4*)(Ai + ch * 32);
      float4 v1 = *(const float4*)(Ai + ch * 32 + 4);
      apk[ch][0][0] = v0.x; apk[ch][0][1] = v0.y;
      apk[ch][1][0] = v0.z; apk[ch][1][1] = v0.w;
      apk[ch][2][0] = v1.x; apk[ch][2][1] = v1.y;
      apk[ch][3][0] = v1.z; apk[ch][3][1] = v1.w;
    }
  }
  // w2 B-frags (bf16) — r9 verbatim
  bf16x8 w2f[4];
  #pragma unroll
  for (int ch = 0; ch < 4; ++ch) {
    #pragma unroll
    for (int e = 0; e < 8; ++e) {
      float wv = (jcol < H_) ? w2[(ch * 32 + lgrp * 8 + e) * H_ + jcol] : 0.0f;
      w2f[ch][e] = f2bf(wv);
    }
  }
  const float b2v = (jcol < H_) ? b2[jcol] : 0.0f;
  float* outp = out + (((size_t)(b * H_ + (jcol & 7)) * S_ + i) * S_)
                + jq * 128 + lgrp * 4;

  __syncthreads();                       // only barrier

  u32x4 cva[4], cvb[4];
  auto LOADT = [&](u32x4 (&dst)[4], int jt) {
    const short* bp = cbf + (jt * 16 + jcol) * D_;
    #pragma unroll
    for (int ch = 0; ch < 4; ++ch)
      dst[ch] = *(const u32x4*)(bp + (((ch * 4 + lgrp) ^ sw) * 8));
  };
  auto COMPUTE = [&](u32x4 (&cv)[4], int jt) {   // r9 verbatim
    f32x4 acc = {0.f, 0.f, 0.f, 0.f};
    #pragma unroll
    for (int ch = 0; ch < 4; ++ch) {
      u32x4 hfd;
      #pragma unroll
      for (int p = 0; p < 4; ++p) {
        unsigned int d = cv[ch][p];
        f32x2 v;
        v[0] = __builtin_bit_cast(float, d << 16);
        v[1] = __builtin_bit_cast(float, d & 0xffff0000u);
        v += apk[ch][p];
        hfd[p] = cvt_pk_bf16(fmaxf(v[0], 0.f), fmaxf(v[1], 0.f));
      }
      bf16x8 hf = __builtin_bit_cast(bf16x8, hfd);
      acc = __builtin_amdgcn_mfma_f32_16x16x32_bf16(hf, w2f[ch], acc, 0, 0, 0);
    }
    if (jcol < H_) {
      float4 o;
      o.x = fsigmoid(acc[0] + b2v);
      o.y = fsigmoid(acc[1] + b2v);
      o.z = fsigmoid(acc[2] + b2v);
      o.w = fsigmoid(acc[3] + b2v);
      *(float4*)(outp + jt * 16) = o;
    }
  };

  LOADT(cva, 0);
  #pragma unroll 1
  for (int jt = 0; jt < 8; jt += 2) {
    LOADT(cvb, jt + 1);
    COMPUTE(cva, jt);
    LOADT(cva, (jt + 2) & 7);            // wrap harmless
    COMPUTE(cvb, jt + 1);
  }
}

extern "C" void kernel_launch(void* const* d_in, const int* in_sizes, int n_in,
                              void* d_out, int out_size, void* d_ws, size_t ws_size,
                              hipStream_t stream) {
  const float* x  = (const float*)d_in[0];
  const float* w1 = (const float*)d_in[1];
  const float* b1 = (const float*)d_in[2];
  const float* w2 = (const float*)d_in[3];
  const float* b2 = (const float*)d_in[4];
  float* out = (float*)d_out;
  float* Aq  = (float*)d_ws;                // 2048*128 f32 = 1 MB
  short* Cbf = (short*)(Aq + B_ * S_ * D_); // + 512 KB bf16
  proj_kernel<<<(B_ * S_) / 4, 256, 0, stream>>>(x, w1, b1, Aq, Cbf);
  edge_kernel<<<B_ * 4 * 64, 512, 0, stream>>>(Aq, Cbf, w2, b2, out);
}

// Round 19
// 36.963 us; speedup vs baseline: 2.7306x; 2.3973x over previous
//
#include <hip/hip_runtime.h>
#include <hip/hip_bf16.h>

#define D_ 128
#define S_ 512
#define B_ 4
#define H_ 8

typedef short bf16x8 __attribute__((ext_vector_type(8)));
typedef unsigned int u32x4 __attribute__((ext_vector_type(4)));
typedef float f32x4 __attribute__((ext_vector_type(4)));
typedef float f32x2 __attribute__((ext_vector_type(2)));

__device__ __forceinline__ short f2bf(float f) {
  __hip_bfloat16 h = __float2bfloat16(f);
  return __builtin_bit_cast(short, h);
}
__device__ __forceinline__ float fsigmoid(float x) {
  return __builtin_amdgcn_rcpf(1.0f + __expf(-x));
}
// HW packed f32->bf16 (RNE) — verified r9/r14.
__device__ __forceinline__ unsigned int cvt_pk_bf16(float lo, float hi) {
  unsigned int r;
  asm("v_cvt_pk_bf16_f32 %0, %1, %2" : "=v"(r) : "v"(lo), "v"(hi));
  return r;
}

// Proj v2 (r9 verbatim, verified): A (+b1) -> f32 Aq, C -> f32 Cq.
// 512 blocks x 256 thr, k-quarter split; w1 read once per block.
__global__ __launch_bounds__(256)
void proj_kernel(const float* __restrict__ x, const float* __restrict__ w1,
                 const float* __restrict__ b1, float* __restrict__ Aq,
                 float* __restrict__ Cq) {
  __shared__ float xs[4 * D_];
  __shared__ f32x4 red[256][5];
  const int t = threadIdx.x;
  const int row0 = blockIdx.x * 4;
  ((float2*)xs)[t] = ((const float2*)(x + row0 * D_))[t];
  __syncthreads();
  const int combo = t & 63;
  const int e4 = (combo & 31) * 4;
  const int half = combo >> 5;
  const int kq = t >> 6;
  const float* w1p = w1 + (half * D_ + kq * 32) * D_ + e4;
  const float* xq = xs + kq * 32;
  f32x4 acc[4] = {};
  #pragma unroll 8
  for (int k = 0; k < 32; ++k) {
    float4 wv = *(const float4*)(w1p + k * D_);
    #pragma unroll
    for (int r = 0; r < 4; ++r) {
      float xv = xq[r * D_ + k];
      acc[r][0] += xv * wv.x; acc[r][1] += xv * wv.y;
      acc[r][2] += xv * wv.z; acc[r][3] += xv * wv.w;
    }
  }
  #pragma unroll
  for (int r = 0; r < 4; ++r) red[t][r] = acc[r];
  __syncthreads();
  const int r = t >> 6;
  const int c2 = t & 63;
  f32x4 s = red[c2][r];
  #pragma unroll
  for (int q = 1; q < 4; ++q) {
    f32x4 v = red[c2 + 64 * q][r];
    s[0] += v[0]; s[1] += v[1]; s[2] += v[2]; s[3] += v[3];
  }
  const int fe4 = (c2 & 31) * 4;
  const int row = row0 + r;
  if ((c2 >> 5) == 0) {
    float4 bv = *(const float4*)(b1 + fe4);
    s[0] += bv.x; s[1] += bv.y; s[2] += bv.z; s[3] += bv.w;
    *(f32x4*)(Aq + row * D_ + fe4) = s;
  } else {
    *(f32x4*)(Cq + row * D_ + fe4) = s;
  }
}

// Edge v9: j-QUARTER, C staged as **f32** in 64 KB LDS (pure copy, swizzled
// phys_u = u ^ (row&7), u in 0..31 16B-units) -> 2 blocks/CU at
// launch_bounds(512,4) (128-VGPR cap, NO spill — r18 lesson: 64-cap spills).
// H-formation drops the 2 unpack bitops per pair (6 -> 4 VALU): c is f32.
// Single-buffered fragments (saves 32 VGPR; 16 waves/CU TLP hides LDS lat).
// MFMA A: row=lane&15 (=j), k=8*(lane>>4)+e. D: col=lane&15 (=h),
// row=(lane>>4)*4+reg. (verified r2-r17)
__global__ __launch_bounds__(512, 4)
void edge_kernel(const float* __restrict__ Aq, const float* __restrict__ Cq,
                 const float* __restrict__ w2, const float* __restrict__ b2,
                 float* __restrict__ out) {
  __shared__ float cs[128 * D_];         // 64 KB f32
  const int t = threadIdx.x;
  const int lane = t & 63;
  const int wid = t >> 6;                // 0..7
  const int b  = blockIdx.x >> 8;
  const int jq = (blockIdx.x >> 6) & 3;  // j quarter
  const int ig = blockIdx.x & 63;
  const int i  = ig * 8 + wid;

  const int jcol = lane & 15;            // j within tile == output h
  const int lgrp = lane >> 4;            // k-group
  const int sw = jcol & 7;

  // ---- stage C quarter f32 (pure copy, swizzled): 4096 units / 512 thr
  {
    const float* cb = Cq + (size_t)(b * S_ + jq * 128) * D_;
    #pragma unroll
    for (int it = 0; it < 8; ++it) {
      int p = t + it * 512;
      int row = p >> 5, u = p & 31;      // 32 x 16B-units per row
      float4 v = *(const float4*)(cb + row * D_ + u * 4);
      *(float4*)(cs + row * D_ + ((u ^ (row & 7)) * 4)) = v;
    }
  }

  // a registers as packed f32x2 (b1 folded in proj) — r9 verbatim
  f32x2 apk[4][4];
  {
    const float* Ai = Aq + (b * S_ + i) * D_ + lgrp * 8;
    #pragma unroll
    for (int ch = 0; ch < 4; ++ch) {
      float4 v0 = *(const float4*)(Ai + ch * 32);
      float4 v1 = *(const float4*)(Ai + ch * 32 + 4);
      apk[ch][0][0] = v0.x; apk[ch][0][1] = v0.y;
      apk[ch][1][0] = v0.z; apk[ch][1][1] = v0.w;
      apk[ch][2][0] = v1.x; apk[ch][2][1] = v1.y;
      apk[ch][3][0] = v1.z; apk[ch][3][1] = v1.w;
    }
  }
  // w2 B-frags (bf16) — r9 verbatim
  bf16x8 w2f[4];
  #pragma unroll
  for (int ch = 0; ch < 4; ++ch) {
    #pragma unroll
    for (int e = 0; e < 8; ++e) {
      float wv = (jcol < H_) ? w2[(ch * 32 + lgrp * 8 + e) * H_ + jcol] : 0.0f;
      w2f[ch][e] = f2bf(wv);
    }
  }
  const float b2v = (jcol < H_) ? b2[jcol] : 0.0f;
  float* outp = out + (((size_t)(b * H_ + (jcol & 7)) * S_ + i) * S_)
                + jq * 128 + lgrp * 4;

  __syncthreads();                       // only barrier

  #pragma unroll 1
  for (int jt = 0; jt < 8; ++jt) {
    const float* bp = cs + (jt * 16 + jcol) * D_;
    f32x4 acc = {0.f, 0.f, 0.f, 0.f};
    #pragma unroll
    for (int ch = 0; ch < 4; ++ch) {
      const int u0 = ch * 8 + lgrp * 2;  // logical 16B-unit (even)
      float4 c0 = *(const float4*)(bp + ((u0 ^ sw) * 4));
      float4 c1 = *(const float4*)(bp + (((u0 + 1) ^ sw) * 4));
      u32x4 hfd;
      f32x2 v;
      v[0] = c0.x; v[1] = c0.y; v += apk[ch][0];
      hfd[0] = cvt_pk_bf16(fmaxf(v[0], 0.f), fmaxf(v[1], 0.f));
      v[0] = c0.z; v[1] = c0.w; v += apk[ch][1];
      hfd[1] = cvt_pk_bf16(fmaxf(v[0], 0.f), fmaxf(v[1], 0.f));
      v[0] = c1.x; v[1] = c1.y; v += apk[ch][2];
      hfd[2] = cvt_pk_bf16(fmaxf(v[0], 0.f), fmaxf(v[1], 0.f));
      v[0] = c1.z; v[1] = c1.w; v += apk[ch][3];
      hfd[3] = cvt_pk_bf16(fmaxf(v[0], 0.f), fmaxf(v[1], 0.f));
      bf16x8 hf = __builtin_bit_cast(bf16x8, hfd);
      acc = __builtin_amdgcn_mfma_f32_16x16x32_bf16(hf, w2f[ch], acc, 0, 0, 0);
    }
    if (jcol < H_) {
      float4 o;
      o.x = fsigmoid(acc[0] + b2v);
      o.y = fsigmoid(acc[1] + b2v);
      o.z = fsigmoid(acc[2] + b2v);
      o.w = fsigmoid(acc[3] + b2v);
      *(float4*)(outp + jt * 16) = o;
    }
  }
}

extern "C" void kernel_launch(void* const* d_in, const int* in_sizes, int n_in,
                              void* d_out, int out_size, void* d_ws, size_t ws_size,
                              hipStream_t stream) {
  const float* x  = (const float*)d_in[0];
  const float* w1 = (const float*)d_in[1];
  const float* b1 = (const float*)d_in[2];
  const float* w2 = (const float*)d_in[3];
  const float* b2 = (const float*)d_in[4];
  float* out = (float*)d_out;
  float* Aq = (float*)d_ws;                 // 2048*128 f32 = 1 MB
  float* Cq = Aq + B_ * S_ * D_;            // +1 MB
  proj_kernel<<<(B_ * S_) / 4, 256, 0, stream>>>(x, w1, b1, Aq, Cq);
  edge_kernel<<<B_ * 4 * 64, 512, 0, stream>>>(Aq, Cq, w2, b2, out);
}